// Round 1
// baseline (308.628 us; speedup 1.0000x reference)
//
#include <hip/hip_runtime.h>

typedef _Float16 f16;
typedef _Float16 f16x8 __attribute__((ext_vector_type(8)));
typedef float f32x4 __attribute__((ext_vector_type(4)));

#define HEADS 32
#define SEQ   2048
#define DIM   64
#define QT    64
#define KTILE 64
#define L2E   1.44269504088896340736f

__device__ __forceinline__ void gload_lds16(const void* gsrc, void* ldst) {
  __builtin_amdgcn_global_load_lds((__attribute__((address_space(1))) void*)gsrc,
                                   (__attribute__((address_space(3))) void*)ldst, 16, 0, 0);
}

// Kernel 0: k (fp32 row-major) -> kt (f16, per-row XOR-swizzled for LDS staging)
//           v (fp32 [kv][d])   -> vt (f16 transposed [d][kv])
__global__ __launch_bounds__(256) void prep_kernel(const float* __restrict__ k,
                                                   const float* __restrict__ v,
                                                   char* __restrict__ kt,
                                                   f16* __restrict__ vt) {
  int n = blockIdx.x * 256 + threadIdx.x;
  const int HALF = HEADS * SEQ * (DIM / 8);  // 524288
  if (n < HALF) {
    int d8 = (n & 7) * 8;
    int kv = (n >> 3) & (SEQ - 1);
    int h  = n >> 14;
    const float* src = k + ((size_t)(h * SEQ + kv)) * DIM + d8;
    float4 a = *(const float4*)src;
    float4 b = *(const float4*)(src + 4);
    f16x8 o;
    o[0]=(f16)a.x; o[1]=(f16)a.y; o[2]=(f16)a.z; o[3]=(f16)a.w;
    o[4]=(f16)b.x; o[5]=(f16)b.y; o[6]=(f16)b.z; o[7]=(f16)b.w;
    *(f16x8*)(kt + ((size_t)(h * SEQ + kv)) * 128 + ((d8 * 2) ^ ((kv & 7) << 4))) = o;
  } else {
    int m = n - HALF;
    int d   = m & 63;
    int kv8 = ((m >> 6) & 255) * 8;
    int h   = m >> 14;
    const float* src = v + ((size_t)(h * SEQ + kv8)) * DIM + d;
    f16x8 o;
#pragma unroll
    for (int i = 0; i < 8; i++) o[i] = (f16)src[i * DIM];
    *(f16x8*)(vt + ((size_t)(h * DIM + d)) * SEQ + kv8) = o;
  }
}

__global__ __launch_bounds__(256) void attn_kernel(const float* __restrict__ q,
                                                   const char* __restrict__ kt,
                                                   const f16* __restrict__ vt,
                                                   float* __restrict__ out_o,
                                                   float* __restrict__ out_p) {
  __shared__ char lds_k[KTILE * 128];  // 8 KB f16 K-tile [kv][d], swizzled
  __shared__ char lds_p[QT * 128];     // 8 KB f16 P-tile [qrow][kv], swizzled, wave-private rows

  const int tid = threadIdx.x;
  const int w = tid >> 6;   // wave 0..3
  const int l = tid & 63;
  const int g = l >> 4;     // 16-lane group
  const int c = l & 15;

  const int head = blockIdx.x >> 5;
  const int qt   = blockIdx.x & 31;
  const int q0   = qt * QT;

  // ---- Q A-fragments (lane c = q-row, g = k-chunk), kept in regs for the whole kernel
  f16x8 qa[2];
  {
    const float* qp = q + ((size_t)(head * SEQ + q0 + w * 16 + c)) * DIM + g * 8;
#pragma unroll
    for (int kc = 0; kc < 2; kc++) {
      float4 a = *(const float4*)(qp + kc * 32);
      float4 b = *(const float4*)(qp + kc * 32 + 4);
      qa[kc][0]=(f16)a.x; qa[kc][1]=(f16)a.y; qa[kc][2]=(f16)a.z; qa[kc][3]=(f16)a.w;
      qa[kc][4]=(f16)b.x; qa[kc][5]=(f16)b.y; qa[kc][6]=(f16)b.z; qa[kc][7]=(f16)b.w;
    }
  }

  const char* kthead = kt + (size_t)head * SEQ * 128;

  f32x4 m_run = {-1e30f, -1e30f, -1e30f, -1e30f};
  f32x4 l_run = {0.f, 0.f, 0.f, 0.f};

  // ================= pass 1: row max + sum =================
  for (int kvb = 0; kvb < SEQ / KTILE; kvb++) {
    const char* ktile = kthead + (size_t)kvb * KTILE * 128;
    gload_lds16(ktile + w * 1024 + l * 16, lds_k + w * 1024);
    gload_lds16(ktile + 4096 + w * 1024 + l * 16, lds_k + 4096 + w * 1024);
    __syncthreads();

    f32x4 sc[4];
#pragma unroll
    for (int f = 0; f < 4; f++) sc[f] = (f32x4){0.f, 0.f, 0.f, 0.f};
#pragma unroll
    for (int kc = 0; kc < 2; kc++) {
#pragma unroll
      for (int f = 0; f < 4; f++) {
        int row = f * 16 + c;
        f16x8 kb = *(const f16x8*)(lds_k + row * 128 + ((kc * 64 + g * 16) ^ ((row & 7) << 4)));
        sc[f] = __builtin_amdgcn_mfma_f32_16x16x32_f16(qa[kc], kb, sc[f], 0, 0, 0);
      }
    }
    __syncthreads();

    f32x4 bm;
#pragma unroll
    for (int r = 0; r < 4; r++)
      bm[r] = fmaxf(fmaxf(sc[0][r], sc[1][r]), fmaxf(sc[2][r], sc[3][r]));
#pragma unroll
    for (int d = 1; d < 16; d <<= 1)
#pragma unroll
      for (int r = 0; r < 4; r++)
        bm[r] = fmaxf(bm[r], __shfl_xor(bm[r], d, 64));
    f32x4 mnew, es = {0.f, 0.f, 0.f, 0.f};
#pragma unroll
    for (int r = 0; r < 4; r++) mnew[r] = fmaxf(m_run[r], bm[r]);
#pragma unroll
    for (int f = 0; f < 4; f++)
#pragma unroll
      for (int r = 0; r < 4; r++)
        es[r] += __builtin_amdgcn_exp2f((sc[f][r] - mnew[r]) * L2E);
#pragma unroll
    for (int d = 1; d < 16; d <<= 1)
#pragma unroll
      for (int r = 0; r < 4; r++)
        es[r] += __shfl_xor(es[r], d, 64);
#pragma unroll
    for (int r = 0; r < 4; r++)
      l_run[r] = l_run[r] * __builtin_amdgcn_exp2f((m_run[r] - mnew[r]) * L2E) + es[r];
    m_run = mnew;
  }

  f32x4 rinv;
#pragma unroll
  for (int r = 0; r < 4; r++) rinv[r] = 1.0f / l_run[r];

  f32x4 o_acc[4];
#pragma unroll
  for (int f = 0; f < 4; f++) o_acc[f] = (f32x4){0.f, 0.f, 0.f, 0.f};

  const f16* vhead = vt + (size_t)head * DIM * SEQ;

  // ================= pass 2: probs write + PV =================
  for (int kvb = 0; kvb < SEQ / KTILE; kvb++) {
    const char* ktile = kthead + (size_t)kvb * KTILE * 128;
    gload_lds16(ktile + w * 1024 + l * 16, lds_k + w * 1024);
    gload_lds16(ktile + 4096 + w * 1024 + l * 16, lds_k + 4096 + w * 1024);
    __syncthreads();

    f32x4 sc[4];
#pragma unroll
    for (int f = 0; f < 4; f++) sc[f] = (f32x4){0.f, 0.f, 0.f, 0.f};
#pragma unroll
    for (int kc = 0; kc < 2; kc++) {
#pragma unroll
      for (int f = 0; f < 4; f++) {
        int row = f * 16 + c;
        f16x8 kb = *(const f16x8*)(lds_k + row * 128 + ((kc * 64 + g * 16) ^ ((row & 7) << 4)));
        sc[f] = __builtin_amdgcn_mfma_f32_16x16x32_f16(qa[kc], kb, sc[f], 0, 0, 0);
      }
    }

    // p = exp(s - m) / l   (fp32, exact softmax of the f16-score matmul)
    f32x4 p[4];
#pragma unroll
    for (int f = 0; f < 4; f++)
#pragma unroll
      for (int r = 0; r < 4; r++)
        p[f][r] = __builtin_amdgcn_exp2f((sc[f][r] - m_run[r]) * L2E) * rinv[r];

    // fp32 probs -> HBM (C-layout: col = c + 16f, row = 4g + r)
#pragma unroll
    for (int f = 0; f < 4; f++)
#pragma unroll
      for (int r = 0; r < 4; r++)
        out_p[((size_t)(head * SEQ + q0 + w * 16 + 4 * g + r)) * SEQ + kvb * KTILE + f * 16 + c] = p[f][r];

    // f16 P tile into wave-private LDS rows (swizzled)
#pragma unroll
    for (int f = 0; f < 4; f++)
#pragma unroll
      for (int r = 0; r < 4; r++) {
        int rowL = w * 16 + 4 * g + r;
        *(f16*)(lds_p + rowL * 128 + (((f * 16 + c) * 2) ^ ((rowL & 7) << 4))) = (f16)p[f][r];
      }
    asm volatile("" ::: "memory");  // keep LDS write->read order (same wave, HW in-order)

    // PV: A = P rows (lane c = q-row), B = V columns from vt
    {
      int rowA = w * 16 + c;
#pragma unroll
      for (int kc = 0; kc < 2; kc++) {
        f16x8 pa = *(const f16x8*)(lds_p + rowA * 128 + ((kc * 64 + g * 16) ^ ((c & 7) << 4)));
#pragma unroll
        for (int f = 0; f < 4; f++) {
          const f16* vp = vhead + (size_t)(f * 16 + c) * SEQ + kvb * KTILE + kc * 32 + g * 8;
          f16x8 vb = *(const f16x8*)vp;
          o_acc[f] = __builtin_amdgcn_mfma_f32_16x16x32_f16(pa, vb, o_acc[f], 0, 0, 0);
        }
      }
    }
    __syncthreads();
  }

  // epilogue: O
#pragma unroll
  for (int f = 0; f < 4; f++)
#pragma unroll
    for (int r = 0; r < 4; r++)
      out_o[((size_t)(head * SEQ + q0 + w * 16 + 4 * g + r)) * DIM + f * 16 + c] = o_acc[f][r];
}

extern "C" void kernel_launch(void* const* d_in, const int* in_sizes, int n_in,
                              void* d_out, int out_size, void* d_ws, size_t ws_size,
                              hipStream_t stream) {
  const float* k = (const float*)d_in[0];
  const float* q = (const float*)d_in[1];
  const float* v = (const float*)d_in[2];
  float* out_o = (float*)d_out;
  float* out_p = out_o + (size_t)HEADS * SEQ * DIM;  // 4,194,304

  char* kt = (char*)d_ws;                                   // 8 MB swizzled f16 K
  f16*  vt = (f16*)(kt + (size_t)HEADS * SEQ * DIM * 2);    // 8 MB f16 V^T

  prep_kernel<<<dim3(4096), dim3(256), 0, stream>>>(k, v, kt, vt);
  attn_kernel<<<dim3(1024), dim3(256), 0, stream>>>(q, kt, vt, out_o, out_p);
}

// Round 3
// 187.092 us; speedup vs baseline: 1.6496x; 1.6496x over previous
//
#include <hip/hip_runtime.h>

typedef _Float16 f16;
typedef _Float16 f16x8 __attribute__((ext_vector_type(8)));
typedef float f32x4 __attribute__((ext_vector_type(4)));

#define HEADS 32
#define SEQ   2048
#define DIM   64
#define QT    64
#define KT    64
#define NT    (SEQ / KT)
#define L2E   1.44269504088896340736f

__device__ __forceinline__ void gload_lds16(const void* gsrc, void* ldst) {
  __builtin_amdgcn_global_load_lds((__attribute__((address_space(1))) void*)gsrc,
                                   (__attribute__((address_space(3))) void*)ldst, 16, 0, 0);
}

// Kernel 0: k (fp32 row-major) -> kt (f16, per-row XOR-swizzled for LDS staging)
//           v (fp32 [kv][d])   -> vt (f16 transposed [d][kv])
__global__ __launch_bounds__(256) void prep_kernel(const float* __restrict__ k,
                                                   const float* __restrict__ v,
                                                   char* __restrict__ kt,
                                                   f16* __restrict__ vt) {
  int n = blockIdx.x * 256 + threadIdx.x;
  const int HALF = HEADS * SEQ * (DIM / 8);  // 524288
  if (n < HALF) {
    int d8 = (n & 7) * 8;
    int kv = (n >> 3) & (SEQ - 1);
    int h  = n >> 14;
    const float* src = k + ((size_t)(h * SEQ + kv)) * DIM + d8;
    float4 a = *(const float4*)src;
    float4 b = *(const float4*)(src + 4);
    f16x8 o;
    o[0]=(f16)a.x; o[1]=(f16)a.y; o[2]=(f16)a.z; o[3]=(f16)a.w;
    o[4]=(f16)b.x; o[5]=(f16)b.y; o[6]=(f16)b.z; o[7]=(f16)b.w;
    *(f16x8*)(kt + ((size_t)(h * SEQ + kv)) * 128 + ((d8 * 2) ^ ((kv & 7) << 4))) = o;
  } else {
    int m = n - HALF;
    int d   = m & 63;
    int kv8 = ((m >> 6) & 255) * 8;
    int h   = m >> 14;
    const float* src = v + ((size_t)(h * SEQ + kv8)) * DIM + d;
    f16x8 o;
#pragma unroll
    for (int i = 0; i < 8; i++) o[i] = (f16)src[i * DIM];
    *(f16x8*)(vt + ((size_t)(h * DIM + d)) * SEQ + kv8) = o;
  }
}

#define STAGE(t, buf)                                                                  \
  do {                                                                                 \
    const char* ktile_ = kthead + (size_t)(t) * KT * 128;                              \
    gload_lds16(ktile_ + w * 1024 + l * 16, &lds_k[buf][w * 1024 + l * 16]);           \
    gload_lds16(ktile_ + 4096 + w * 1024 + l * 16, &lds_k[buf][4096 + w * 1024 + l * 16]); \
  } while (0)

#define QKT(buf)                                                                       \
  do {                                                                                 \
    _Pragma("unroll") for (int kc = 0; kc < 2; kc++) {                                 \
      _Pragma("unroll") for (int f = 0; f < 4; f++) {                                  \
        int row_ = f * 16 + c;                                                         \
        f16x8 kb_ = *(const f16x8*)&lds_k[buf][row_ * 128 +                            \
                       ((kc * 64 + g * 16) ^ ((row_ & 7) << 4))];                      \
        sc[f] = __builtin_amdgcn_mfma_f32_16x16x32_f16(qa[kc], kb_, sc[f], 0, 0, 0);   \
      }                                                                                \
    }                                                                                  \
  } while (0)

__global__ __launch_bounds__(256, 4) void attn_kernel(const float* __restrict__ q,
                                                      const char* __restrict__ kt,
                                                      const f16* __restrict__ vt,
                                                      float* __restrict__ out_o,
                                                      float* __restrict__ out_p) {
  __shared__ char  lds_k[2][KT * 128];  // 2 x 8 KB swizzled f16 K tiles (double buffer)
  __shared__ float lds_pt[QT * 64];     // 16 KB fp32 P transpose buf, chunk-XOR-swizzled

  const int tid = threadIdx.x;
  const int w = tid >> 6;   // wave 0..3
  const int l = tid & 63;
  const int g = l >> 4;     // 16-lane group
  const int c = l & 15;

  const int head = blockIdx.x >> 5;
  const int q0   = (blockIdx.x & 31) * QT;

  // Q A-fragments (lane c = q-row, g = k-chunk), in regs for whole kernel
  f16x8 qa[2];
  {
    const float* qp = q + ((size_t)(head * SEQ + q0 + w * 16 + c)) * DIM + g * 8;
#pragma unroll
    for (int kc = 0; kc < 2; kc++) {
      float4 a = *(const float4*)(qp + kc * 32);
      float4 b = *(const float4*)(qp + kc * 32 + 4);
      qa[kc][0]=(f16)a.x; qa[kc][1]=(f16)a.y; qa[kc][2]=(f16)a.z; qa[kc][3]=(f16)a.w;
      qa[kc][4]=(f16)b.x; qa[kc][5]=(f16)b.y; qa[kc][6]=(f16)b.z; qa[kc][7]=(f16)b.w;
    }
  }

  const char* kthead = kt + (size_t)head * SEQ * 128;

  // per-lane online softmax state: row q = 4g+r held in lanes sharing g
  float m_ln[4] = {-1e30f, -1e30f, -1e30f, -1e30f};
  float l_ln[4] = {0.f, 0.f, 0.f, 0.f};

  // ================= pass 1: per-lane online m/l (no cross-lane in loop) ==========
  STAGE(0, 0);
  __syncthreads();
  for (int t = 0; t < NT; t++) {
    int cur = t & 1;
    if (t + 1 < NT) STAGE(t + 1, cur ^ 1);
    f32x4 sc[4];
#pragma unroll
    for (int f = 0; f < 4; f++) sc[f] = (f32x4){0.f, 0.f, 0.f, 0.f};
    QKT(cur);
#pragma unroll
    for (int r = 0; r < 4; r++) {
      float tm = fmaxf(fmaxf(sc[0][r], sc[1][r]), fmaxf(sc[2][r], sc[3][r]));
      float mn = fmaxf(m_ln[r], tm);
      float acc = l_ln[r] * __builtin_amdgcn_exp2f((m_ln[r] - mn) * L2E);
#pragma unroll
      for (int f = 0; f < 4; f++)
        acc += __builtin_amdgcn_exp2f((sc[f][r] - mn) * L2E);
      l_ln[r] = acc;
      m_ln[r] = mn;
    }
    __syncthreads();
  }

  // cross-lane finalize (once): reduce over the 16 lanes sharing g
  f32x4 m_run, rinv;
#pragma unroll
  for (int r = 0; r < 4; r++) {
    float mf = m_ln[r];
#pragma unroll
    for (int d = 1; d < 16; d <<= 1) mf = fmaxf(mf, __shfl_xor(mf, d, 64));
    float lv = l_ln[r] * __builtin_amdgcn_exp2f((m_ln[r] - mf) * L2E);
#pragma unroll
    for (int d = 1; d < 16; d <<= 1) lv += __shfl_xor(lv, d, 64);
    m_run[r] = mf;
    rinv[r]  = 1.0f / lv;
  }

  f32x4 o_acc[4];
#pragma unroll
  for (int f = 0; f < 4; f++) o_acc[f] = (f32x4){0.f, 0.f, 0.f, 0.f};

  const f16* vhead = vt + (size_t)head * DIM * SEQ;
  float* prow = out_p + (size_t)(head * SEQ + q0) * SEQ;

  // ================= pass 2: probs (coalesced nt stores) + PV =====================
  STAGE(0, 0);
  __syncthreads();
  for (int t = 0; t < NT; t++) {
    int cur = t & 1;
    if (t + 1 < NT) STAGE(t + 1, cur ^ 1);
    f32x4 sc[4];
#pragma unroll
    for (int f = 0; f < 4; f++) sc[f] = (f32x4){0.f, 0.f, 0.f, 0.f};
    QKT(cur);

    // p = exp2((s - m)*log2e) * rinv -> swizzled fp32 LDS (wave-private rows)
#pragma unroll
    for (int f = 0; f < 4; f++)
#pragma unroll
      for (int r = 0; r < 4; r++) {
        float pv = __builtin_amdgcn_exp2f((sc[f][r] - m_run[r]) * L2E) * rinv[r];
        int rowL = w * 16 + 4 * g + r;
        lds_pt[rowL * 64 + ((16 * f + c) ^ ((rowL & 7) << 2))] = pv;
      }
    asm volatile("" ::: "memory");

    // coalesced probs store: 4 x dwordx4 per lane, 256B contiguous per row, nt
#pragma unroll
    for (int j = 0; j < 4; j++) {
      int rowL = w * 16 + j * 4 + g;
      f32x4 pv4 = *(const f32x4*)&lds_pt[rowL * 64 + ((c ^ (rowL & 7)) << 2)];
      __builtin_nontemporal_store(pv4, (f32x4*)&prow[(size_t)rowL * SEQ + t * 64 + c * 4]);
    }

    // PV: A-frag = P row (lane c = q-row) read back from swizzled LDS, cvt f16
    {
      int rowA = w * 16 + c;
      int sw = c & 7;
#pragma unroll
      for (int kc = 0; kc < 2; kc++) {
        f32x4 a0 = *(const f32x4*)&lds_pt[rowA * 64 + (((8 * kc + 2 * g) ^ sw) << 2)];
        f32x4 a1 = *(const f32x4*)&lds_pt[rowA * 64 + (((8 * kc + 2 * g + 1) ^ sw) << 2)];
        f16x8 pa;
        pa[0]=(f16)a0[0]; pa[1]=(f16)a0[1]; pa[2]=(f16)a0[2]; pa[3]=(f16)a0[3];
        pa[4]=(f16)a1[0]; pa[5]=(f16)a1[1]; pa[6]=(f16)a1[2]; pa[7]=(f16)a1[3];
#pragma unroll
        for (int f = 0; f < 4; f++) {
          f16x8 vb = *(const f16x8*)(vhead + (size_t)(f * 16 + c) * SEQ + t * 64 + kc * 32 + g * 8);
          o_acc[f] = __builtin_amdgcn_mfma_f32_16x16x32_f16(pa, vb, o_acc[f], 0, 0, 0);
        }
      }
    }
    __syncthreads();
  }

  // ============ O epilogue: same LDS transpose -> coalesced nt float4 stores ======
#pragma unroll
  for (int f = 0; f < 4; f++)
#pragma unroll
    for (int r = 0; r < 4; r++) {
      int rowL = w * 16 + 4 * g + r;
      lds_pt[rowL * 64 + ((16 * f + c) ^ ((rowL & 7) << 2))] = o_acc[f][r];
    }
  asm volatile("" ::: "memory");
#pragma unroll
  for (int j = 0; j < 4; j++) {
    int rowL = w * 16 + j * 4 + g;
    f32x4 ov = *(const f32x4*)&lds_pt[rowL * 64 + ((c ^ (rowL & 7)) << 2)];
    __builtin_nontemporal_store(ov, (f32x4*)&out_o[(size_t)(head * SEQ + q0 + rowL) * DIM + c * 4]);
  }
}

extern "C" void kernel_launch(void* const* d_in, const int* in_sizes, int n_in,
                              void* d_out, int out_size, void* d_ws, size_t ws_size,
                              hipStream_t stream) {
  const float* k = (const float*)d_in[0];
  const float* q = (const float*)d_in[1];
  const float* v = (const float*)d_in[2];
  float* out_o = (float*)d_out;
  float* out_p = out_o + (size_t)HEADS * SEQ * DIM;  // 4,194,304

  char* kt = (char*)d_ws;                                   // 8 MB swizzled f16 K
  f16*  vt = (f16*)(kt + (size_t)HEADS * SEQ * DIM * 2);    // 8 MB f16 V^T

  prep_kernel<<<dim3(4096), dim3(256), 0, stream>>>(k, v, kt, vt);
  attn_kernel<<<dim3(1024), dim3(256), 0, stream>>>(q, kt, vt, out_o, out_p);
}